// Round 7
// baseline (624.404 us; speedup 1.0000x reference)
//
#include <hip/hip_runtime.h>
#include <hip/hip_bf16.h>

typedef __bf16 bf16_t;
typedef __bf16 bf16x8 __attribute__((ext_vector_type(8)));
typedef float  f32x4  __attribute__((ext_vector_type(4)));

constexpr int S  = 2048;
constexpr int H  = 32;
constexpr int D  = 128;
constexpr int BR = 128;   // q rows per tile
constexpr int SC = 32;    // kv positions per chunk
constexpr int NT = S / BR;        // 16 q-tiles
constexpr int KSTR  = 144;        // Klds row stride (elems); 72 dwords -> bank
                                  // stride 8: 4-way K-read aliasing (was 8-way @136)
constexpr int VSTR2 = 20;         // Vt2 row stride (dwords)

constexpr size_t WS_LBYTES = (size_t)S * H * sizeof(float);   // 262144 B row-sums

__device__ __forceinline__ bf16x8 cvt8(f32x4 lo, f32x4 hi) {
    bf16x8 r;
#pragma unroll
    for (int j = 0; j < 4; ++j) { r[j] = (bf16_t)lo[j]; r[4 + j] = (bf16_t)hi[j]; }
    return r;
}
__device__ __forceinline__ uint32_t pk2(float a, float b) {
    union { uint32_t u; bf16_t h[2]; } r;
    r.h[0] = (bf16_t)a; r.h[1] = (bf16_t)b;   // kv even -> low, kv odd -> high
    return r.u;
}

// Flash attention fwd, f32 I/O, bf16 MFMA, S^T orientation, 32 q rows/wave.
//
// DS-PIPE THEORY (rounds 0/2/5: dur 91/84/83 us at occupancy 14/28/35% --
// occupancy moved, dur didn't): the shared LDS pipe is the wall. 16 ds_read
// _b128 per wave-chunk at ~12cyc + 46K conflict cyc/CU ~= 70 us of the 83.
// FIX: 2 q-groups per wave (round-0 inner loop) -- same 16 reads feed 32
// MFMA instead of 16, halving DS reads per unit work.
//
// BALANCE kept from round 5 (proven: zero-tail): pair (pr,15-pr) = 68
// chunks -> 4 equal windows of 17; grid 1024 x 256thr (4 waves x 32 q),
// 4 blocks/CU, 16 waves/CU. A window may span the tile boundary -> up to
// 2 segments. All segments atomicAdd unnormalized O into out (zeroed by
// hipMemsetAsync) + row-sums l into ws; fa_norm divides at the end.
// Fixed-max softmax (exp2 clamped) is LINEAR in kv -> partials add.
//
// P never touches LDS: K rows staged under permutation
//   pi^-1(kv) = (kv&4) ? 16 + 4*(kv>>3) + (kv&3) : 4*(kv>>3) + (kv&3)
// so the S^T C-fragment holds exactly the kv = quad*8 + j values the PV
// B-fragment needs, in register order {frag0[0..3], frag1[0..3]}.
__global__ __launch_bounds__(256)
__attribute__((amdgpu_waves_per_eu(4, 4)))
void fa_bal(const float* __restrict__ q, const float* __restrict__ kvp,
            float* __restrict__ out, float* __restrict__ lws) {
    __shared__ __align__(16) bf16_t   Klds[2][SC * KSTR];  // 2 x 9216 B
    __shared__ __align__(16) uint32_t Vt2[2][D * VSTR2];   // 2 x 10240 B

    const int bx  = blockIdx.x;
    const int h   = bx & 31;                // heads innermost (same-h blocks
    const int u   = bx >> 5;                //   share an XCD L2: kv head = 2.1MB)
    const int pr  = u >> 2;                 // 0..7 tile pair (pr, 15-pr)
    const int win = u & 3;                  // kv window within the pair

    const int t    = threadIdx.x;           // 0..255
    const int w    = t >> 6;                // 0..3
    const int lane = t & 63;
    const int quad = lane >> 4;
    const int m    = lane & 15;

    const float sc = 0.08838834764831845f * 1.44269504088896340f; // scale*log2e

    // staging geometry (round-1 proven): thread stages K/V rows {2k2, 2k2+1},
    // d-cols kc*8..+7
    const int k2 = t >> 4, kc = t & 15;
    const int r0 = 2 * k2;
    const int lr0 = ((r0 >> 3) << 2) + (r0 & 3) + ((r0 & 4) ? 16 : 0); // pi^-1
    const int vpos = k2 ^ ((kc & 3) << 2);        // Vt2 column swizzle
    const bool hb  = (kc & 4) != 0;               // V-write bank-spread bit

    const size_t rowstep = (size_t)2 * H * D;     // f32 elems per kv row
    const size_t cstep   = (size_t)SC * rowstep;  // one 32-kv chunk

    f32x4 kr[2][2], vr[2][2];
    const float* pk;
    const float* pv;
    auto ldregs = [&]() {
        kr[0][0] = *(const f32x4*)pk;             kr[0][1] = *(const f32x4*)(pk + 4);
        kr[1][0] = *(const f32x4*)(pk + rowstep); kr[1][1] = *(const f32x4*)(pk + rowstep + 4);
        vr[0][0] = *(const f32x4*)pv;             vr[0][1] = *(const f32x4*)(pv + 4);
        vr[1][0] = *(const f32x4*)(pv + rowstep); vr[1][1] = *(const f32x4*)(pv + rowstep + 4);
    };
    auto stage = [&](int b) {
        *(bf16x8*)&Klds[b][lr0       * KSTR + kc * 8] = cvt8(kr[0][0], kr[0][1]);
        *(bf16x8*)&Klds[b][(lr0 + 1) * KSTR + kc * 8] = cvt8(kr[1][0], kr[1][1]);
        // hb reorder spreads V-write banks: (20jq + 16hb + vpos) mod 32
        f32x4 aA = hb ? vr[0][1] : vr[0][0];
        f32x4 bA = hb ? vr[1][1] : vr[1][0];
        f32x4 aB = hb ? vr[0][0] : vr[0][1];
        f32x4 bB = hb ? vr[1][0] : vr[1][1];
        const int dA = kc * 8 + (hb ? 4 : 0);
        const int dB = kc * 8 + (hb ? 0 : 4);
#pragma unroll
        for (int jq = 0; jq < 4; ++jq) {
            Vt2[b][(dA + jq) * VSTR2 + vpos] = pk2(aA[jq], bA[jq]);
            Vt2[b][(dB + jq) * VSTR2 + vpos] = pk2(aB[jq], bB[jq]);
        }
    };

    // pair chunk-space: [0, b) = tile pr, [b, 68) = tile 15-pr
    const int b    = 4 * pr + 4;
    const int wbeg = 17 * win, wend = wbeg + 17;

    for (int s = 0; s < 2; ++s) {
        const int cb = s ? (wbeg > b ? wbeg : b) : wbeg;
        const int ce = s ? wend : (wend < b ? wend : b);
        const int n  = ce - cb;
        if (n <= 0) continue;                   // block-uniform: barriers safe
        const int tile = s ? (15 - pr) : pr;
        const int lb   = cb - (s ? b : 0);      // tile-local first chunk
        const int q0   = tile * BR;
        const int qp0  = q0 + w * 32 + m;
        const int qmaxw = q0 + w * 32 + 31;

        pk = kvp + (((size_t)r0 * 2 + 0) * H + h) * D + kc * 8 + (size_t)lb * cstep;
        pv = kvp + (((size_t)r0 * 2 + 1) * H + h) * D + kc * 8 + (size_t)lb * cstep;

        // ---- Q fragments (B-operand of S^T), 2 groups x 4 d-chunks, pre-scaled
        bf16x8 aq[2][4];
#pragma unroll
        for (int g = 0; g < 2; ++g)
#pragma unroll
            for (int c = 0; c < 4; ++c) {
                const float* p = q + ((size_t)(qp0 + g * 16) * H + h) * D + c * 32 + quad * 8;
                f32x4 lo = *(const f32x4*)p * sc;
                f32x4 hi = *(const f32x4*)(p + 4) * sc;
                aq[g][c] = cvt8(lo, hi);
            }

        f32x4 o[2][8];
#pragma unroll
        for (int g = 0; g < 2; ++g)
#pragma unroll
            for (int idx = 0; idx < 8; ++idx) o[g][idx] = (f32x4)0.f;
        float lrow[2] = {0.f, 0.f};

        // ---- pipeline head: chunk lb staged in bank 0, lb+1 in registers
        ldregs();
        stage(0);
        if (n > 1) { pk += cstep; pv += cstep; ldregs(); }
        __syncthreads();

        for (int it = 0; it < n; ++it) {
            const int kv0 = (lb + it) * SC;
            const int cur = it & 1;
            const bool active = (kv0 <= qmaxw);

            bf16x8 bp0, bp1;
            if (active) {
                // ---- S^T = K Q^T : K fragments read once, feed both q-groups
                f32x4 sA[2][2];
#pragma unroll
                for (int g = 0; g < 2; ++g) { sA[g][0] = (f32x4)0.f; sA[g][1] = (f32x4)0.f; }
                __builtin_amdgcn_s_setprio(1);
#pragma unroll
                for (int c = 0; c < 4; ++c) {
                    bf16x8 ak0 = *(const bf16x8*)&Klds[cur][m * KSTR + c * 32 + quad * 8];
                    bf16x8 ak1 = *(const bf16x8*)&Klds[cur][(16 + m) * KSTR + c * 32 + quad * 8];
                    sA[0][0] = __builtin_amdgcn_mfma_f32_16x16x32_bf16(ak0, aq[0][c], sA[0][0], 0, 0, 0);
                    sA[0][1] = __builtin_amdgcn_mfma_f32_16x16x32_bf16(ak1, aq[0][c], sA[0][1], 0, 0, 0);
                    sA[1][0] = __builtin_amdgcn_mfma_f32_16x16x32_bf16(ak0, aq[1][c], sA[1][0], 0, 0, 0);
                    sA[1][1] = __builtin_amdgcn_mfma_f32_16x16x32_bf16(ak1, aq[1][c], sA[1][1], 0, 0, 0);
                }
                __builtin_amdgcn_s_setprio(0);

                // ---- fixed-max softmax: p = exp2(min(v,80)); frag0 <-> kv 8q+r,
                // frag1 <-> kv 8q+4+r (K-row permutation). Full tiles skip mask.
#pragma unroll
                for (int g = 0; g < 2; ++g) {
                    const int limb = q0 + w * 32 + g * 16 - kv0;   // wave-uniform
                    float p[8], rs = 0.f;
                    if (limb >= 31) {
#pragma unroll
                        for (int r = 0; r < 4; ++r) {
                            p[r]     = __builtin_amdgcn_exp2f(fminf(sA[g][0][r], 80.f));
                            p[4 + r] = __builtin_amdgcn_exp2f(fminf(sA[g][1][r], 80.f));
                            rs += p[r] + p[4 + r];
                        }
                    } else {
                        const int lim = limb + m;
#pragma unroll
                        for (int r = 0; r < 4; ++r) {
                            float e0 = __builtin_amdgcn_exp2f(fminf(sA[g][0][r], 80.f));
                            float e1 = __builtin_amdgcn_exp2f(fminf(sA[g][1][r], 80.f));
                            p[r]     = (quad * 8 + r     <= lim) ? e0 : 0.f;
                            p[4 + r] = (quad * 8 + 4 + r <= lim) ? e1 : 0.f;
                            rs += p[r] + p[4 + r];
                        }
                    }
                    lrow[g] += rs;
                    bf16x8 bv;
#pragma unroll
                    for (int r = 0; r < 4; ++r) { bv[r] = (bf16_t)p[r]; bv[4 + r] = (bf16_t)p[4 + r]; }
                    if (g == 0) bp0 = bv; else bp1 = bv;
                }
            }

            // ---- stage chunk it+1 into other bank; prefetch it+2 (all waves)
            if (it + 1 < n) {
                stage(cur ^ 1);
                if (it + 2 < n) { pk += cstep; pv += cstep; ldregs(); }
            }

            if (active) {
                // ---- O^T += V^T P^T; V fragments read once, feed both groups
                __builtin_amdgcn_s_setprio(1);
#pragma unroll
                for (int tt = 0; tt < 8; ++tt) {
                    const int dd  = tt * 16 + m;
                    const int grp = quad ^ ((dd >> 3) & 3);
                    bf16x8 av = *(const bf16x8*)&Vt2[cur][dd * VSTR2 + grp * 4];
                    o[0][tt] = __builtin_amdgcn_mfma_f32_16x16x32_bf16(av, bp0, o[0][tt], 0, 0, 0);
                    o[1][tt] = __builtin_amdgcn_mfma_f32_16x16x32_bf16(av, bp1, o[1][tt], 0, 0, 0);
                }
                __builtin_amdgcn_s_setprio(0);
            }
            __syncthreads();
        }

        // ---- epilogue: atomically accumulate unnormalized partials.
        // O^T layout col=q=m, row=d=quad*4+r.
#pragma unroll
        for (int g = 0; g < 2; ++g) {
            lrow[g] += __shfl_xor(lrow[g], 16);
            lrow[g] += __shfl_xor(lrow[g], 32);
            float* op = out + ((size_t)(qp0 + g * 16) * H + h) * D;
#pragma unroll
            for (int tt = 0; tt < 8; ++tt)
#pragma unroll
                for (int j = 0; j < 4; ++j)
                    atomicAdd(op + tt * 16 + quad * 4 + j, o[g][tt][j]);
            if (quad == 0)
                atomicAdd(&lws[(size_t)(qp0 + g * 16) * H + h], lrow[g]);
        }
    }
}

// normalize: out[q,h,d] /= l[q,h]
__global__ __launch_bounds__(256)
void fa_norm(float* __restrict__ out, const float* __restrict__ lws) {
    const int idx = blockIdx.x * 256 + threadIdx.x;   // one f32x4 each
    const int d4 = idx & 31;
    const int hh = (idx >> 5) & 31;
    const int qq = idx >> 10;
    const float inv = 1.0f / lws[qq * 32 + hh];
    f32x4 v = *((const f32x4*)out + idx);
    *((f32x4*)out + idx) = v * inv;
    (void)d4;
}

// fallback: round-2 kernel verbatim (used when ws unavailable)
__global__ __launch_bounds__(512)
__attribute__((amdgpu_waves_per_eu(4, 4)))
void fa_fwd_r2(const float* __restrict__ q, const float* __restrict__ kvp,
               float* __restrict__ out) {
    __shared__ __align__(16) bf16_t   Klds[2][SC * 136];
    __shared__ __align__(16) uint32_t Vt2[2][D * VSTR2];

    const int bx = blockIdx.x;
    const int h  = bx & 31;
    const int i  = bx >> 5;
    const int qtile = (i < 8) ? (15 - i) : (i - 8);
    const int q0    = qtile * BR;

    const int t    = threadIdx.x;
    const int w    = t >> 6;
    const int lane = t & 63;
    const int quad = lane >> 4;
    const int m    = lane & 15;

    const float sc = 0.08838834764831845f * 1.44269504088896340f;

    const int rk  = t >> 4;
    const int kc  = t & 15;
    const int lrk = ((rk >> 3) << 2) + (rk & 3) + ((rk & 4) ? 16 : 0);
    const int vp  = t >> 5;
    const int dh  = t & 31;
    const int d0v = dh * 4;
    const int vpos = vp ^ (((dh >> 1) & 3) << 2);

    const size_t rowstep = (size_t)2 * H * D;
    const size_t tstep   = (size_t)SC * rowstep;
    const float* pk  = kvp + (((size_t)rk * 2 + 0) * H + h) * D + kc * 8;
    const float* pv0 = kvp + (((size_t)(2 * vp) * 2 + 1) * H + h) * D + d0v;

    const int qp0   = q0 + w * 16 + m;
    const int nkv   = (qtile + 1) * (BR / SC);
    const int qmaxw = q0 + w * 16 + 15;

    bf16x8 aq[4];
#pragma unroll
    for (int c = 0; c < 4; ++c) {
        const float* p = q + ((size_t)qp0 * H + h) * D + c * 32 + quad * 8;
        f32x4 lo = *(const f32x4*)p * sc;
        f32x4 hi = *(const f32x4*)(p + 4) * sc;
        aq[c] = cvt8(lo, hi);
    }

    f32x4 o[8];
#pragma unroll
    for (int idx = 0; idx < 8; ++idx) o[idx] = (f32x4)0.f;
    float lrow = 0.f;

    f32x4 kr[2], vr0, vr1;
    auto ldregs = [&]() {
        kr[0] = *(const f32x4*)pk;
        kr[1] = *(const f32x4*)(pk + 4);
        vr0   = *(const f32x4*)pv0;
        vr1   = *(const f32x4*)(pv0 + rowstep);
    };
    auto stage = [&](int bb) {
        *(bf16x8*)&Klds[bb][lrk * 136 + kc * 8] = cvt8(kr[0], kr[1]);
#pragma unroll
        for (int jq = 0; jq < 4; ++jq)
            Vt2[bb][(d0v + jq) * VSTR2 + vpos] = pk2(vr0[jq], vr1[jq]);
    };

    ldregs();
    stage(0);
    if (nkv > 1) { pk += tstep; pv0 += tstep; ldregs(); }
    __syncthreads();

    for (int kb = 0; kb < nkv; ++kb) {
        const int kv0 = kb * SC;
        const int cur = kb & 1;
        const bool active = (kv0 <= qmaxw);

        bf16x8 bp;
        if (active) {
            f32x4 sA[2];
            sA[0] = (f32x4)0.f; sA[1] = (f32x4)0.f;
            __builtin_amdgcn_s_setprio(1);
#pragma unroll
            for (int c = 0; c < 4; ++c) {
                bf16x8 ak0 = *(const bf16x8*)&Klds[cur][m * 136 + c * 32 + quad * 8];
                bf16x8 ak1 = *(const bf16x8*)&Klds[cur][(16 + m) * 136 + c * 32 + quad * 8];
                sA[0] = __builtin_amdgcn_mfma_f32_16x16x32_bf16(ak0, aq[c], sA[0], 0, 0, 0);
                sA[1] = __builtin_amdgcn_mfma_f32_16x16x32_bf16(ak1, aq[c], sA[1], 0, 0, 0);
            }
            __builtin_amdgcn_s_setprio(0);

            const int limb = q0 + w * 16 - kv0;
            float p[8], rs = 0.f;
            if (limb >= 31) {
#pragma unroll
                for (int r = 0; r < 4; ++r) {
                    p[r]     = __builtin_amdgcn_exp2f(fminf(sA[0][r], 80.f));
                    p[4 + r] = __builtin_amdgcn_exp2f(fminf(sA[1][r], 80.f));
                    rs += p[r] + p[4 + r];
                }
            } else {
                const int lim = limb + m;
#pragma unroll
                for (int r = 0; r < 4; ++r) {
                    float e0 = __builtin_amdgcn_exp2f(fminf(sA[0][r], 80.f));
                    float e1 = __builtin_amdgcn_exp2f(fminf(sA[1][r], 80.f));
                    p[r]     = (quad * 8 + r     <= lim) ? e0 : 0.f;
                    p[4 + r] = (quad * 8 + 4 + r <= lim) ? e1 : 0.f;
                    rs += p[r] + p[4 + r];
                }
            }
            lrow += rs;
#pragma unroll
            for (int r = 0; r < 4; ++r) { bp[r] = (bf16_t)p[r]; bp[4 + r] = (bf16_t)p[4 + r]; }
        }

        if (kb + 1 < nkv) {
            stage(cur ^ 1);
            if (kb + 2 < nkv) { pk += tstep; pv0 += tstep; ldregs(); }
        }

        if (active) {
            __builtin_amdgcn_s_setprio(1);
#pragma unroll
            for (int tt = 0; tt < 8; ++tt) {
                const int dd  = tt * 16 + m;
                const int grp = quad ^ ((dd >> 3) & 3);
                bf16x8 av = *(const bf16x8*)&Vt2[cur][dd * VSTR2 + grp * 4];
                o[tt] = __builtin_amdgcn_mfma_f32_16x16x32_bf16(av, bp, o[tt], 0, 0, 0);
            }
            __builtin_amdgcn_s_setprio(0);
        }
        __syncthreads();
    }

    lrow += __shfl_xor(lrow, 16);
    lrow += __shfl_xor(lrow, 32);

    {
        const float inv = 1.0f / lrow;
        float* op = out + ((size_t)qp0 * H + h) * D;
#pragma unroll
        for (int tt = 0; tt < 8; ++tt) {
            f32x4 val = o[tt] * inv;
            *(f32x4*)(op + tt * 16 + quad * 4) = val;
        }
    }
}

extern "C" void kernel_launch(void* const* d_in, const int* in_sizes, int n_in,
                              void* d_out, int out_size, void* d_ws, size_t ws_size,
                              hipStream_t stream) {
    const float* q  = (const float*)d_in[0];
    const float* kv = (const float*)d_in[1];
    float* out = (float*)d_out;
    if (d_ws != nullptr && ws_size >= WS_LBYTES) {
        hipMemsetAsync(d_out, 0, (size_t)out_size, stream);
        hipMemsetAsync(d_ws, 0, WS_LBYTES, stream);
        fa_bal<<<dim3(1024), dim3(256), 0, stream>>>(q, kv, out, (float*)d_ws);
        fa_norm<<<dim3((S * H * D / 4) / 256), dim3(256), 0, stream>>>(out, (const float*)d_ws);
    } else {
        fa_fwd_r2<<<dim3(NT * H), dim3(512), 0, stream>>>(q, kv, out);
    }
}

// Round 8
// 180.925 us; speedup vs baseline: 3.4512x; 3.4512x over previous
//
#include <hip/hip_runtime.h>
#include <hip/hip_bf16.h>

typedef __bf16 bf16_t;
typedef __bf16 bf16x8 __attribute__((ext_vector_type(8)));
typedef float  f32x4  __attribute__((ext_vector_type(4)));

constexpr int S  = 2048;
constexpr int H  = 32;
constexpr int D  = 128;
constexpr int BR = 128;   // q rows per tile (32 per wave, 4 waves)
constexpr int SC = 32;    // kv positions per chunk
constexpr int NT = S / BR;        // 16 q-tiles
constexpr int KSTR  = 144;        // Klds row stride; bank stride 8 dwords
constexpr int VSTR2 = 20;         // Vt2 row stride (dwords)

// workspace layout (f32 indices): O_B partials, then l_A, then l_B
constexpr size_t WS_OB  = 0;                              // [pr][h][128r][128d]
constexpr size_t WS_LA  = (size_t)8 * 32 * 128 * 128;     // [pr][h][128r]
constexpr size_t WS_LB  = WS_LA + (size_t)8 * 32 * 128;
constexpr size_t WS_F32 = WS_LB + (size_t)8 * 32 * 128;   // 4,202,496 f32

__device__ __forceinline__ bf16x8 cvt8(f32x4 lo, f32x4 hi) {
    bf16x8 r;
#pragma unroll
    for (int j = 0; j < 4; ++j) { r[j] = (bf16_t)lo[j]; r[4 + j] = (bf16_t)hi[j]; }
    return r;
}
__device__ __forceinline__ uint32_t pk2(float a, float b) {
    union { uint32_t u; bf16_t h[2]; } r;
    r.h[0] = (bf16_t)a; r.h[1] = (bf16_t)b;   // kv even -> low, kv odd -> high
    return r.u;
}

// Flash attention fwd, f32 I/O, bf16 MFMA, S^T orientation, 32 q rows/wave.
//
// Synthesis of everything proven so far:
//  * 32-q waves (round-0 inner loop): each K/V ds_read_b128 feeds TWO MFMA
//    -- DS-read work per unit of output is HALF of the 16-q variants
//    (rounds 2/5 at 83-84 us were DS-pipe-bound: 139K wave-chunks x 16KB
//    reads ~= 50us/CU + conflicts; 32-q waves make it 69.6K).
//  * Balanced grid via round-5-PROVEN A/B split + f32 ws merge (no atomics,
//    deterministic): pair (pr,15-pr) = 68 chunks; A = tile pr (4pr+4) +
//    first 30-4pr of tile 15-pr; B = last 34 of tile 15-pr. 512 blocks,
//    all exactly 34 chunks. A's big-tile prefix is provably full-causal
//    (min q row 1920-128pr > max kv 959-128pr) -> no-mask fast path.
//  * Codegen: __launch_bounds__(256,2) ONLY -- the (256,4)/waves_per_eu(4,4)
//    variants twice produced 64-VGPR spilling builds (rounds 1/6, +scratch
//    traffic in WRITE_SIZE). Round 0 proved this exact loop at 112 VGPR.
//  * KSTR=144 (bank stride 8): fewer K-read conflicts than 136 (round 6:
//    3.2M vs 11.9M).
//
// P never touches LDS: K rows staged under permutation
//   pi^-1(kv) = (kv&4) ? 16 + 4*(kv>>3) + (kv&3) : 4*(kv>>3) + (kv&3)
// so the S^T C-fragment holds exactly the kv = quad*8 + j values the PV
// B-fragment needs, in register order {frag0[0..3], frag1[0..3]}.
__global__ __launch_bounds__(256, 2)
void fa_bal(const float* __restrict__ q, const float* __restrict__ kvp,
            float* __restrict__ out, float* __restrict__ ws) {
    __shared__ __align__(16) bf16_t   Klds[2][SC * KSTR];  // 2 x 9216 B
    __shared__ __align__(16) uint32_t Vt2[2][D * VSTR2];   // 2 x 10240 B

    const int bx   = blockIdx.x;
    const int h    = bx & 31;               // heads innermost
    const int u    = bx >> 5;               // 0..15
    const int pr   = u >> 1;                // 0..7 tile pair (pr, 15-pr)
    const int role = u & 1;                 // 0 = A, 1 = B

    const int t    = threadIdx.x;           // 0..255
    const int w    = t >> 6;                // 0..3
    const int lane = t & 63;
    const int quad = lane >> 4;
    const int m    = lane & 15;

    const float sc = 0.08838834764831845f * 1.44269504088896340f; // scale*log2e

    // staging geometry (round-0 proven): thread stages K/V rows {2k2, 2k2+1},
    // d-cols kc*8..+7
    const int k2 = t >> 4, kc = t & 15;
    const int r0 = 2 * k2;
    const int lr0 = ((r0 >> 3) << 2) + (r0 & 3) + ((r0 & 4) ? 16 : 0); // pi^-1
    const int vpos = k2 ^ ((kc & 3) << 2);        // Vt2 column swizzle
    const bool hb  = (kc & 4) != 0;               // V-write bank-spread bit

    const size_t rowstep = (size_t)2 * H * D;     // f32 elems per kv row
    const size_t cstep   = (size_t)SC * rowstep;  // one 32-kv chunk

    f32x4 kr[2][2], vr[2][2];
    const float* pk;
    const float* pv;
    auto ldregs = [&]() {
        kr[0][0] = *(const f32x4*)pk;             kr[0][1] = *(const f32x4*)(pk + 4);
        kr[1][0] = *(const f32x4*)(pk + rowstep); kr[1][1] = *(const f32x4*)(pk + rowstep + 4);
        vr[0][0] = *(const f32x4*)pv;             vr[0][1] = *(const f32x4*)(pv + 4);
        vr[1][0] = *(const f32x4*)(pv + rowstep); vr[1][1] = *(const f32x4*)(pv + rowstep + 4);
    };
    auto stage = [&](int b) {
        *(bf16x8*)&Klds[b][lr0       * KSTR + kc * 8] = cvt8(kr[0][0], kr[0][1]);
        *(bf16x8*)&Klds[b][(lr0 + 1) * KSTR + kc * 8] = cvt8(kr[1][0], kr[1][1]);
        // hb reorder spreads V-write banks: (20jq + 16hb + vpos) mod 32
        f32x4 aA = hb ? vr[0][1] : vr[0][0];
        f32x4 bA = hb ? vr[1][1] : vr[1][0];
        f32x4 aB = hb ? vr[0][0] : vr[0][1];
        f32x4 bB = hb ? vr[1][0] : vr[1][1];
        const int dA = kc * 8 + (hb ? 4 : 0);
        const int dB = kc * 8 + (hb ? 0 : 4);
#pragma unroll
        for (int jq = 0; jq < 4; ++jq) {
            Vt2[b][(dA + jq) * VSTR2 + vpos] = pk2(aA[jq], bA[jq]);
            Vt2[b][(dB + jq) * VSTR2 + vpos] = pk2(aB[jq], bB[jq]);
        }
    };

    const int nph = (role == 0) ? 2 : 1;
    for (int ph = 0; ph < nph; ++ph) {
        // segment schedule: tile-local chunk window [lb, lb+n); mode = epilogue
        int tile, lb, n, mode;
        if (role == 0) {
            if (ph == 0) { tile = pr;      lb = 0;           n = 4 * pr + 4;  mode = 0; }
            else         { tile = 15 - pr; lb = 0;           n = 30 - 4 * pr; mode = 1; }
        } else           { tile = 15 - pr; lb = 30 - 4 * pr; n = 34;          mode = 2; }

        const int q0    = tile * BR;
        const int qp0   = q0 + w * 32 + m;
        const int qmaxw = q0 + w * 32 + 31;

        pk = kvp + (((size_t)r0 * 2 + 0) * H + h) * D + kc * 8 + (size_t)lb * cstep;
        pv = kvp + (((size_t)r0 * 2 + 1) * H + h) * D + kc * 8 + (size_t)lb * cstep;

        // ---- Q fragments (B-operand of S^T), 2 groups x 4 d-chunks, pre-scaled
        bf16x8 aq[2][4];
#pragma unroll
        for (int g = 0; g < 2; ++g)
#pragma unroll
            for (int c = 0; c < 4; ++c) {
                const float* p = q + ((size_t)(qp0 + g * 16) * H + h) * D + c * 32 + quad * 8;
                f32x4 lo = *(const f32x4*)p * sc;
                f32x4 hi = *(const f32x4*)(p + 4) * sc;
                aq[g][c] = cvt8(lo, hi);
            }

        f32x4 o[2][8];
#pragma unroll
        for (int g = 0; g < 2; ++g)
#pragma unroll
            for (int idx = 0; idx < 8; ++idx) o[g][idx] = (f32x4)0.f;
        float lrow[2] = {0.f, 0.f};

        // ---- pipeline head: chunk lb staged in bank 0, lb+1 in registers
        ldregs();
        stage(0);
        if (n > 1) { pk += cstep; pv += cstep; ldregs(); }
        __syncthreads();

        for (int it = 0; it < n; ++it) {
            const int kv0 = (lb + it) * SC;
            const int cur = it & 1;
            const bool active = (kv0 <= qmaxw);

            bf16x8 bp0, bp1;
            if (active) {
                // ---- S^T = K Q^T : K fragments read once, feed both q-groups
                f32x4 sA[2][2];
#pragma unroll
                for (int g = 0; g < 2; ++g) { sA[g][0] = (f32x4)0.f; sA[g][1] = (f32x4)0.f; }
                __builtin_amdgcn_s_setprio(1);
#pragma unroll
                for (int c = 0; c < 4; ++c) {
                    bf16x8 ak0 = *(const bf16x8*)&Klds[cur][m * KSTR + c * 32 + quad * 8];
                    bf16x8 ak1 = *(const bf16x8*)&Klds[cur][(16 + m) * KSTR + c * 32 + quad * 8];
                    sA[0][0] = __builtin_amdgcn_mfma_f32_16x16x32_bf16(ak0, aq[0][c], sA[0][0], 0, 0, 0);
                    sA[0][1] = __builtin_amdgcn_mfma_f32_16x16x32_bf16(ak1, aq[0][c], sA[0][1], 0, 0, 0);
                    sA[1][0] = __builtin_amdgcn_mfma_f32_16x16x32_bf16(ak0, aq[1][c], sA[1][0], 0, 0, 0);
                    sA[1][1] = __builtin_amdgcn_mfma_f32_16x16x32_bf16(ak1, aq[1][c], sA[1][1], 0, 0, 0);
                }
                __builtin_amdgcn_s_setprio(0);

                // ---- fixed-max softmax: p = exp2(min(v,80)); frag0 <-> kv 8q+r,
                // frag1 <-> kv 8q+4+r (K-row permutation). Full tiles skip mask.
#pragma unroll
                for (int g = 0; g < 2; ++g) {
                    const int limb = q0 + w * 32 + g * 16 - kv0;   // wave-uniform
                    float p[8], rs = 0.f;
                    if (limb >= 31) {
#pragma unroll
                        for (int r = 0; r < 4; ++r) {
                            p[r]     = __builtin_amdgcn_exp2f(fminf(sA[g][0][r], 80.f));
                            p[4 + r] = __builtin_amdgcn_exp2f(fminf(sA[g][1][r], 80.f));
                            rs += p[r] + p[4 + r];
                        }
                    } else {
                        const int lim = limb + m;
#pragma unroll
                        for (int r = 0; r < 4; ++r) {
                            float e0 = __builtin_amdgcn_exp2f(fminf(sA[g][0][r], 80.f));
                            float e1 = __builtin_amdgcn_exp2f(fminf(sA[g][1][r], 80.f));
                            p[r]     = (quad * 8 + r     <= lim) ? e0 : 0.f;
                            p[4 + r] = (quad * 8 + 4 + r <= lim) ? e1 : 0.f;
                            rs += p[r] + p[4 + r];
                        }
                    }
                    lrow[g] += rs;
                    bf16x8 bv;
#pragma unroll
                    for (int r = 0; r < 4; ++r) { bv[r] = (bf16_t)p[r]; bv[4 + r] = (bf16_t)p[4 + r]; }
                    if (g == 0) bp0 = bv; else bp1 = bv;
                }
            }

            // ---- stage chunk it+1 into other bank; prefetch it+2 (all waves)
            if (it + 1 < n) {
                stage(cur ^ 1);
                if (it + 2 < n) { pk += cstep; pv += cstep; ldregs(); }
            }

            if (active) {
                // ---- O^T += V^T P^T; V fragments read once, feed both groups
                __builtin_amdgcn_s_setprio(1);
#pragma unroll
                for (int tt = 0; tt < 8; ++tt) {
                    const int dd  = tt * 16 + m;
                    const int grp = quad ^ ((dd >> 3) & 3);
                    bf16x8 av = *(const bf16x8*)&Vt2[cur][dd * VSTR2 + grp * 4];
                    o[0][tt] = __builtin_amdgcn_mfma_f32_16x16x32_bf16(av, bp0, o[0][tt], 0, 0, 0);
                    o[1][tt] = __builtin_amdgcn_mfma_f32_16x16x32_bf16(av, bp1, o[1][tt], 0, 0, 0);
                }
                __builtin_amdgcn_s_setprio(0);
            }
            __syncthreads();
        }

        // ---- epilogue by mode. O^T layout: col=q=m, row=d=quad*4+r.
        // Each output row touched by exactly one writer per mode -> no atomics.
#pragma unroll
        for (int g = 0; g < 2; ++g) {
            lrow[g] += __shfl_xor(lrow[g], 16);
            lrow[g] += __shfl_xor(lrow[g], 32);
            const int rloc = w * 32 + g * 16 + m;       // row within tile
            if (mode == 0) {        // sole owner: normalize, final store
                const float inv = 1.0f / lrow[g];
                float* op = out + ((size_t)(qp0 + g * 16) * H + h) * D;
#pragma unroll
                for (int tt = 0; tt < 8; ++tt) {
                    f32x4 val = o[g][tt] * inv;
                    *(f32x4*)(op + tt * 16 + quad * 4) = val;
                }
            } else if (mode == 1) { // A: unnormalized partial -> out, l_A -> ws
                float* op = out + ((size_t)(qp0 + g * 16) * H + h) * D;
#pragma unroll
                for (int tt = 0; tt < 8; ++tt)
                    *(f32x4*)(op + tt * 16 + quad * 4) = o[g][tt];
                if (quad == 0)
                    ws[WS_LA + ((size_t)pr * 32 + h) * 128 + rloc] = lrow[g];
            } else {                // B: partial -> ws, l_B -> ws
                float* wp = ws + WS_OB + ((size_t)pr * 32 + h) * 16384
                               + (size_t)rloc * 128;
#pragma unroll
                for (int tt = 0; tt < 8; ++tt)
                    *(f32x4*)(wp + tt * 16 + quad * 4) = o[g][tt];
                if (quad == 0)
                    ws[WS_LB + ((size_t)pr * 32 + h) * 128 + rloc] = lrow[g];
            }
        }
        // next segment's stage(0) only touches LDS; the loop-final barrier
        // already ordered all LDS reads before it.
    }
}

// merge split tiles: out = (out_A + O_B) / (l_A + l_B)   (round-5 proven)
__global__ __launch_bounds__(256)
void fa_merge(float* __restrict__ out, const float* __restrict__ ws) {
    const int mb = blockIdx.x;          // 0..255
    const int pr = mb >> 5, h = mb & 31;
    const int q0 = (15 - pr) * BR;
    const int tid = threadIdx.x;
    const int d4 = tid & 31;            // d = d4*4
    const int rg = tid >> 5;            // 0..7
    const float* lA = ws + WS_LA + ((size_t)pr * 32 + h) * 128;
    const float* lB = ws + WS_LB + ((size_t)pr * 32 + h) * 128;
    const float* OB = ws + WS_OB + ((size_t)pr * 32 + h) * 16384;
#pragma unroll
    for (int k = 0; k < 16; ++k) {
        const int r = rg * 16 + k;
        const float inv = 1.0f / (lA[r] + lB[r]);
        const size_t oidx = ((size_t)(q0 + r) * H + h) * D + d4 * 4;
        f32x4 a = *(const f32x4*)(out + oidx);
        f32x4 b = *(const f32x4*)(OB + (size_t)r * 128 + d4 * 4);
        *(f32x4*)(out + oidx) = (a + b) * inv;
    }
}

// fallback: round-2 kernel verbatim (used when ws unavailable)
__global__ __launch_bounds__(512)
__attribute__((amdgpu_waves_per_eu(4, 4)))
void fa_fwd_r2(const float* __restrict__ q, const float* __restrict__ kvp,
               float* __restrict__ out) {
    __shared__ __align__(16) bf16_t   Klds[2][SC * 136];
    __shared__ __align__(16) uint32_t Vt2[2][D * VSTR2];

    const int bx = blockIdx.x;
    const int h  = bx & 31;
    const int i  = bx >> 5;
    const int qtile = (i < 8) ? (15 - i) : (i - 8);
    const int q0    = qtile * BR;

    const int t    = threadIdx.x;
    const int w    = t >> 6;
    const int lane = t & 63;
    const int quad = lane >> 4;
    const int m    = lane & 15;

    const float sc = 0.08838834764831845f * 1.44269504088896340f;

    const int rk  = t >> 4;
    const int kc  = t & 15;
    const int lrk = ((rk >> 3) << 2) + (rk & 3) + ((rk & 4) ? 16 : 0);
    const int vp  = t >> 5;
    const int dh  = t & 31;
    const int d0v = dh * 4;
    const int vpos = vp ^ (((dh >> 1) & 3) << 2);

    const size_t rowstep = (size_t)2 * H * D;
    const size_t tstep   = (size_t)SC * rowstep;
    const float* pk  = kvp + (((size_t)rk * 2 + 0) * H + h) * D + kc * 8;
    const float* pv0 = kvp + (((size_t)(2 * vp) * 2 + 1) * H + h) * D + d0v;

    const int qp0   = q0 + w * 16 + m;
    const int nkv   = (qtile + 1) * (BR / SC);
    const int qmaxw = q0 + w * 16 + 15;

    bf16x8 aq[4];
#pragma unroll
    for (int c = 0; c < 4; ++c) {
        const float* p = q + ((size_t)qp0 * H + h) * D + c * 32 + quad * 8;
        f32x4 lo = *(const f32x4*)p * sc;
        f32x4 hi = *(const f32x4*)(p + 4) * sc;
        aq[c] = cvt8(lo, hi);
    }

    f32x4 o[8];
#pragma unroll
    for (int idx = 0; idx < 8; ++idx) o[idx] = (f32x4)0.f;
    float lrow = 0.f;

    f32x4 kr[2], vr0, vr1;
    auto ldregs = [&]() {
        kr[0] = *(const f32x4*)pk;
        kr[1] = *(const f32x4*)(pk + 4);
        vr0   = *(const f32x4*)pv0;
        vr1   = *(const f32x4*)(pv0 + rowstep);
    };
    auto stage = [&](int bb) {
        *(bf16x8*)&Klds[bb][lrk * 136 + kc * 8] = cvt8(kr[0], kr[1]);
#pragma unroll
        for (int jq = 0; jq < 4; ++jq)
            Vt2[bb][(d0v + jq) * VSTR2 + vpos] = pk2(vr0[jq], vr1[jq]);
    };

    ldregs();
    stage(0);
    if (nkv > 1) { pk += tstep; pv0 += tstep; ldregs(); }
    __syncthreads();

    for (int kb = 0; kb < nkv; ++kb) {
        const int kv0 = kb * SC;
        const int cur = kb & 1;
        const bool active = (kv0 <= qmaxw);

        bf16x8 bp;
        if (active) {
            f32x4 sA[2];
            sA[0] = (f32x4)0.f; sA[1] = (f32x4)0.f;
            __builtin_amdgcn_s_setprio(1);
#pragma unroll
            for (int c = 0; c < 4; ++c) {
                bf16x8 ak0 = *(const bf16x8*)&Klds[cur][m * 136 + c * 32 + quad * 8];
                bf16x8 ak1 = *(const bf16x8*)&Klds[cur][(16 + m) * 136 + c * 32 + quad * 8];
                sA[0] = __builtin_amdgcn_mfma_f32_16x16x32_bf16(ak0, aq[c], sA[0], 0, 0, 0);
                sA[1] = __builtin_amdgcn_mfma_f32_16x16x32_bf16(ak1, aq[c], sA[1], 0, 0, 0);
            }
            __builtin_amdgcn_s_setprio(0);

            const int limb = q0 + w * 16 - kv0;
            float p[8], rs = 0.f;
            if (limb >= 31) {
#pragma unroll
                for (int r = 0; r < 4; ++r) {
                    p[r]     = __builtin_amdgcn_exp2f(fminf(sA[0][r], 80.f));
                    p[4 + r] = __builtin_amdgcn_exp2f(fminf(sA[1][r], 80.f));
                    rs += p[r] + p[4 + r];
                }
            } else {
                const int lim = limb + m;
#pragma unroll
                for (int r = 0; r < 4; ++r) {
                    float e0 = __builtin_amdgcn_exp2f(fminf(sA[0][r], 80.f));
                    float e1 = __builtin_amdgcn_exp2f(fminf(sA[1][r], 80.f));
                    p[r]     = (quad * 8 + r     <= lim) ? e0 : 0.f;
                    p[4 + r] = (quad * 8 + 4 + r <= lim) ? e1 : 0.f;
                    rs += p[r] + p[4 + r];
                }
            }
            lrow += rs;
#pragma unroll
            for (int r = 0; r < 4; ++r) { bp[r] = (bf16_t)p[r]; bp[4 + r] = (bf16_t)p[4 + r]; }
        }

        if (kb + 1 < nkv) {
            stage(cur ^ 1);
            if (kb + 2 < nkv) { pk += tstep; pv0 += tstep; ldregs(); }
        }

        if (active) {
            __builtin_amdgcn_s_setprio(1);
#pragma unroll
            for (int tt = 0; tt < 8; ++tt) {
                const int dd  = tt * 16 + m;
                const int grp = quad ^ ((dd >> 3) & 3);
                bf16x8 av = *(const bf16x8*)&Vt2[cur][dd * VSTR2 + grp * 4];
                o[tt] = __builtin_amdgcn_mfma_f32_16x16x32_bf16(av, bp, o[tt], 0, 0, 0);
            }
            __builtin_amdgcn_s_setprio(0);
        }
        __syncthreads();
    }

    lrow += __shfl_xor(lrow, 16);
    lrow += __shfl_xor(lrow, 32);

    {
        const float inv = 1.0f / lrow;
        float* op = out + ((size_t)qp0 * H + h) * D;
#pragma unroll
        for (int tt = 0; tt < 8; ++tt) {
            f32x4 val = o[tt] * inv;
            *(f32x4*)(op + tt * 16 + quad * 4) = val;
        }
    }
}

extern "C" void kernel_launch(void* const* d_in, const int* in_sizes, int n_in,
                              void* d_out, int out_size, void* d_ws, size_t ws_size,
                              hipStream_t stream) {
    const float* q  = (const float*)d_in[0];
    const float* kv = (const float*)d_in[1];
    float* out = (float*)d_out;
    if (d_ws != nullptr && ws_size >= WS_F32 * sizeof(float)) {
        fa_bal<<<dim3(512), dim3(256), 0, stream>>>(q, kv, out, (float*)d_ws);
        fa_merge<<<dim3(256), dim3(256), 0, stream>>>(out, (const float*)d_ws);
    } else {
        fa_fwd_r2<<<dim3(NT * H), dim3(512), 0, stream>>>(q, kv, out);
    }
}